// Round 1
// baseline (202.330 us; speedup 1.0000x reference)
//
#include <hip/hip_runtime.h>
#include <hip/hip_bf16.h>

#define NSAMP 128
#define AGENTS 64
#define D 128
#define NN (NSAMP * AGENTS)      // 8192
#define LOG2E 1.44269504088896340736f
#define LN2   0.69314718055994530942f
#define EPSF  1e-5f

// ---------------------------------------------------------------------------
// Kernel 1: per-node linear terms.
//   A_f[n] = x[n]@Wf[0:128]   + centers[n]@Wf[256:258] + bf   (dst side)
//   B_f[n] = x[n]@Wf[128:256] - centers[n]@Wf[256:258]        (src side)
//   same with Ws/bs for A_s, B_s.
// Viewed as C[8192x512] = X[8192x128] @ Weff[128x512] + epilogue.
// grid = 128 mtiles x 8 ntiles (64 cols each); block 256 (16x16, 4x4 micro).
// ---------------------------------------------------------------------------
__global__ __launch_bounds__(256) void prep_kernel(
    const float* __restrict__ x,        // [NN][D]
    const float* __restrict__ centers,  // [NN][2]
    const float* __restrict__ Wf,       // [258][D]
    const float* __restrict__ bf,       // [D]
    const float* __restrict__ Ws,       // [258][D]
    const float* __restrict__ bs,       // [D]
    float* __restrict__ out)            // 4 x [NN][D]: Af,Bf,As,Bs
{
    const int mt  = blockIdx.x >> 3;
    const int nt  = blockIdx.x & 7;
    const int arr = nt >> 1;            // 0:Af 1:Bf 2:As 3:Bs
    const int c0  = (nt & 1) * 64;
    const float* Wsrc = (arr < 2) ? Wf : Ws;
    const int rowoff = (arr & 1) ? D : 0;
    const int m0 = mt * 64;
    const int tid = threadIdx.x;

    __shared__ float Xs[64][132];       // pad 132: 16B-aligned rows, conflict-light
    __shared__ float Wt[128][64];

    // stage X tile 64x128
    #pragma unroll
    for (int i = 0; i < 8; ++i) {
        int f4 = i * 256 + tid;         // 2048 float4
        int idx = f4 * 4;
        int m = idx >> 7, k = idx & 127;
        float4 v = *(const float4*)&x[(size_t)(m0 + m) * D + k];
        *(float4*)&Xs[m][k] = v;
    }
    // stage W tile 128x64
    #pragma unroll
    for (int i = 0; i < 8; ++i) {
        int f4 = i * 256 + tid;
        int idx = f4 * 4;
        int k = idx >> 6, lc = idx & 63;
        float4 v = *(const float4*)&Wsrc[(size_t)(rowoff + k) * D + c0 + lc];
        *(float4*)&Wt[k][lc] = v;
    }
    __syncthreads();

    const int tr = tid >> 4;   // 0..15  -> rows tr*4..tr*4+3
    const int tc = tid & 15;   // 0..15  -> cols tc*4..tc*4+3

    float acc[4][4] = {};
    for (int k = 0; k < D; k += 4) {
        float4 a[4], w[4];
        #pragma unroll
        for (int im = 0; im < 4; ++im) a[im] = *(const float4*)&Xs[tr * 4 + im][k];
        #pragma unroll
        for (int kk = 0; kk < 4; ++kk) w[kk] = *(const float4*)&Wt[k + kk][tc * 4];
        #pragma unroll
        for (int im = 0; im < 4; ++im) {
            const float* ap = (const float*)&a[im];
            #pragma unroll
            for (int kk = 0; kk < 4; ++kk) {
                const float* wp = (const float*)&w[kk];
                float av = ap[kk];
                acc[im][0] = fmaf(av, wp[0], acc[im][0]);
                acc[im][1] = fmaf(av, wp[1], acc[im][1]);
                acc[im][2] = fmaf(av, wp[2], acc[im][2]);
                acc[im][3] = fmaf(av, wp[3], acc[im][3]);
            }
        }
    }

    // epilogue: centers term + bias
    const float sgn = (arr & 1) ? -1.f : 1.f;
    float cw0[4], cw1[4], bias[4];
    #pragma unroll
    for (int jn = 0; jn < 4; ++jn) {
        int c = c0 + tc * 4 + jn;
        cw0[jn] = Wsrc[256 * D + c];
        cw1[jn] = Wsrc[257 * D + c];
        bias[jn] = (arr == 0) ? bf[c] : ((arr == 2) ? bs[c] : 0.f);
    }
    float* obase = out + (size_t)arr * NN * D;
    #pragma unroll
    for (int im = 0; im < 4; ++im) {
        int n = m0 + tr * 4 + im;
        float ce0 = centers[2 * n], ce1 = centers[2 * n + 1];
        float4 v;
        float* vp = (float*)&v;
        #pragma unroll
        for (int jn = 0; jn < 4; ++jn)
            vp[jn] = acc[im][jn] + bias[jn] + sgn * fmaf(ce0, cw0[jn], ce1 * cw1[jn]);
        *(float4*)&obase[(size_t)n * D + c0 + tc * 4] = v;
    }
}

// ---------------------------------------------------------------------------
// Kernel 2: edge aggregation within each 64-agent clique.
//   agg[d][c] = sum_{j != d} sigmoid(Af[d][c]+Bf[j][c]) * softplus(As[d][c]+Bs[j][c])
// Work in log2 space: sig = rcp(1+2^(-t_f*log2e)); sp = log2(1+2^(t_s*log2e));
// multiply by ln2 once at the end. Full j-sum then subtract j=d self term.
// grid = 128 samples x 4 dst-groups; block 256 = 2 dst-halves x 128 channels.
// Each thread owns 8 (d,c) pairs fully -> no atomics for agg.
// Also emits per-block partial sums (s1,s2 per channel) for batch-norm stats.
// ---------------------------------------------------------------------------
__global__ __launch_bounds__(256) void edge_kernel(
    const float* __restrict__ Af, const float* __restrict__ Bf,
    const float* __restrict__ As, const float* __restrict__ Bs,
    float* __restrict__ agg,        // [NN][D]
    float* __restrict__ partials)   // [512][256]: s1[128], s2[128]
{
    const int s = blockIdx.x >> 2;
    const int g = blockIdx.x & 3;
    const int tid = threadIdx.x;
    const int c  = tid & 127;
    const int dh = tid >> 7;
    const int nbase = s * AGENTS;

    __shared__ float Bfs[AGENTS][D];
    __shared__ float Bss[AGENTS][D];

    #pragma unroll
    for (int i = 0; i < 8; ++i) {
        int f4 = i * 256 + tid;
        int idx = f4 * 4;
        int j = idx >> 7, cc = idx & 127;
        *(float4*)&Bfs[j][cc] = *(const float4*)&Bf[(size_t)(nbase + j) * D + cc];
        *(float4*)&Bss[j][cc] = *(const float4*)&Bs[(size_t)(nbase + j) * D + cc];
    }
    __syncthreads();

    const int d0 = g * 16 + dh * 8;
    float afn[8], ask[8], acc[8];
    #pragma unroll
    for (int i = 0; i < 8; ++i) {
        int n = nbase + d0 + i;
        afn[i] = -LOG2E * Af[(size_t)n * D + c];
        ask[i] =  LOG2E * As[(size_t)n * D + c];
        acc[i] = 0.f;
    }

    for (int j = 0; j < AGENTS; ++j) {
        float bfn = -LOG2E * Bfs[j][c];
        float bsk =  LOG2E * Bss[j][c];
        #pragma unroll
        for (int i = 0; i < 8; ++i) {
            float ef = __builtin_amdgcn_exp2f(afn[i] + bfn);
            float sg = __builtin_amdgcn_rcpf(1.f + ef);
            float es = __builtin_amdgcn_exp2f(ask[i] + bsk);
            float lg = __builtin_amdgcn_logf(1.f + es);
            acc[i] += sg * lg;
        }
    }

    // subtract self term, scale by ln2, store agg, accumulate stats
    float s1 = 0.f, s2 = 0.f;
    #pragma unroll
    for (int i = 0; i < 8; ++i) {
        int j = d0 + i;
        float bfn = -LOG2E * Bfs[j][c];
        float bsk =  LOG2E * Bss[j][c];
        float ef = __builtin_amdgcn_exp2f(afn[i] + bfn);
        float sg = __builtin_amdgcn_rcpf(1.f + ef);
        float es = __builtin_amdgcn_exp2f(ask[i] + bsk);
        float lg = __builtin_amdgcn_logf(1.f + es);
        float a = (acc[i] - sg * lg) * LN2;
        agg[(size_t)(nbase + d0 + i) * D + c] = a;
        s1 += a;
        s2 += a * a;
    }

    __syncthreads();               // done reading B tiles; reuse LDS
    if (dh == 1) { Bfs[0][c] = s1; Bss[0][c] = s2; }
    __syncthreads();
    if (dh == 0) {
        s1 += Bfs[0][c];
        s2 += Bss[0][c];
        partials[(size_t)blockIdx.x * 256 + c]       = s1;
        partials[(size_t)blockIdx.x * 256 + 128 + c] = s2;
    }
}

// ---------------------------------------------------------------------------
// Kernel 3: reduce 512 partials -> mu[c], rstd[c].  grid 128 (c), block 256.
// ---------------------------------------------------------------------------
__global__ __launch_bounds__(256) void stats_kernel(
    const float* __restrict__ partials, float* __restrict__ stats)
{
    const int c = blockIdx.x;
    const int t = threadIdx.x;
    float s1 = partials[(size_t)t * 256 + c] + partials[(size_t)(t + 256) * 256 + c];
    float s2 = partials[(size_t)t * 256 + 128 + c] + partials[(size_t)(t + 256) * 256 + 128 + c];
    __shared__ float r1[256], r2[256];
    r1[t] = s1; r2[t] = s2;
    __syncthreads();
    for (int off = 128; off > 0; off >>= 1) {
        if (t < off) { r1[t] += r1[t + off]; r2[t] += r2[t + off]; }
        __syncthreads();
    }
    if (t == 0) {
        float mu = r1[0] * (1.f / NN);
        float var = r2[0] * (1.f / NN) - mu * mu;
        stats[c]     = mu;
        stats[D + c] = rsqrtf(var + EPSF);
    }
}

// ---------------------------------------------------------------------------
// Kernel 4: BN + residual + relu.  out = relu((agg-mu)*rstd*gamma + beta + x)
// grid 1024, block 256, float4 per thread.
// ---------------------------------------------------------------------------
__global__ __launch_bounds__(256) void bn_kernel(
    const float* __restrict__ agg, const float* __restrict__ xin,
    const float* __restrict__ stats,
    const float* __restrict__ gamma, const float* __restrict__ beta,
    float* __restrict__ outp)
{
    const int t = blockIdx.x * 256 + threadIdx.x;
    const int n = t >> 5;
    const int c = (t & 31) * 4;
    float4 a  = *(const float4*)&agg[(size_t)n * D + c];
    float4 xv = *(const float4*)&xin[(size_t)n * D + c];
    float4 mu = *(const float4*)&stats[c];
    float4 rs = *(const float4*)&stats[D + c];
    float4 gm = *(const float4*)&gamma[c];
    float4 bt = *(const float4*)&beta[c];
    float4 o;
    o.x = fmaxf(0.f, fmaf((a.x - mu.x) * rs.x, gm.x, bt.x) + xv.x);
    o.y = fmaxf(0.f, fmaf((a.y - mu.y) * rs.y, gm.y, bt.y) + xv.y);
    o.z = fmaxf(0.f, fmaf((a.z - mu.z) * rs.z, gm.z, bt.z) + xv.z);
    o.w = fmaxf(0.f, fmaf((a.w - mu.w) * rs.w, gm.w, bt.w) + xv.w);
    *(float4*)&outp[(size_t)n * D + c] = o;
}

// ---------------------------------------------------------------------------
extern "C" void kernel_launch(void* const* d_in, const int* in_sizes, int n_in,
                              void* d_out, int out_size, void* d_ws, size_t ws_size,
                              hipStream_t stream) {
    const float* x0      = (const float*)d_in[0];
    const float* centers = (const float*)d_in[1];
    // d_in[2], d_in[3]: edge lists — structure is deterministic, unused.
    const float* Wf[2] = { (const float*)d_in[4],  (const float*)d_in[10] };
    const float* bf[2] = { (const float*)d_in[5],  (const float*)d_in[11] };
    const float* Ws[2] = { (const float*)d_in[6],  (const float*)d_in[12] };
    const float* bs[2] = { (const float*)d_in[7],  (const float*)d_in[13] };
    const float* gm[2] = { (const float*)d_in[8],  (const float*)d_in[14] };
    const float* bt[2] = { (const float*)d_in[9],  (const float*)d_in[15] };

    float* ws       = (float*)d_ws;
    const size_t ND = (size_t)NN * D;     // 1048576
    float* AB       = ws;                 // 4*ND floats
    float* agg      = ws + 4 * ND;
    float* x1       = ws + 5 * ND;
    float* partials = ws + 6 * ND;        // 512*256
    float* stats    = partials + 512 * 256;

    float* outp = (float*)d_out;

    const float* xin = x0;
    for (int l = 0; l < 2; ++l) {
        float* xout = (l == 0) ? x1 : outp;
        prep_kernel<<<dim3(1024), dim3(256), 0, stream>>>(
            xin, centers, Wf[l], bf[l], Ws[l], bs[l], AB);
        edge_kernel<<<dim3(512), dim3(256), 0, stream>>>(
            AB, AB + ND, AB + 2 * ND, AB + 3 * ND, agg, partials);
        stats_kernel<<<dim3(128), dim3(256), 0, stream>>>(partials, stats);
        bn_kernel<<<dim3(1024), dim3(256), 0, stream>>>(
            agg, xin, stats, gm[l], bt[l], xout);
        xin = x1;
    }
}

// Round 2
// 179.951 us; speedup vs baseline: 1.1244x; 1.1244x over previous
//
#include <hip/hip_runtime.h>
#include <hip/hip_bf16.h>

#define NSAMP 128
#define AGENTS 64
#define D 128
#define NN (NSAMP * AGENTS)      // 8192
#define LOG2E 1.44269504088896340736f
#define LN2   0.69314718055994530942f
#define EPSF  1e-5f

// ---------------------------------------------------------------------------
// Kernel 1: per-node linear terms, exponentiated.
//   Af[n] = x[n]@Wf[0:128]   + centers[n]@Wf[256:258] + bf   (dst side)
//   Bf[n] = x[n]@Wf[128:256] - centers[n]@Wf[256:258]        (src side)
//   same with Ws/bs for As, Bs.  Stores:
//     EAf = exp2(-log2e*Af), EBf = exp2(-log2e*Bf)   (for sigmoid)
//     EAs = exp2(+log2e*As), EBs = exp2(+log2e*Bs)   (for softplus)
// so the edge loop needs no exp2: e^{-(Af+Bf)} = EAf*EBf etc.
// Viewed as C[8192x512] = X[8192x128] @ Weff[128x512] + epilogue.
// grid = 128 mtiles x 8 ntiles (64 cols each); block 256 (16x16, 4x4 micro).
// ---------------------------------------------------------------------------
__global__ __launch_bounds__(256) void prep_kernel(
    const float* __restrict__ x,        // [NN][D]
    const float* __restrict__ centers,  // [NN][2]
    const float* __restrict__ Wf,       // [258][D]
    const float* __restrict__ bf,       // [D]
    const float* __restrict__ Ws,       // [258][D]
    const float* __restrict__ bs,       // [D]
    float* __restrict__ out)            // 4 x [NN][D]: EAf,EBf,EAs,EBs
{
    const int mt  = blockIdx.x >> 3;
    const int nt  = blockIdx.x & 7;
    const int arr = nt >> 1;            // 0:EAf 1:EBf 2:EAs 3:EBs
    const int c0  = (nt & 1) * 64;
    const float* Wsrc = (arr < 2) ? Wf : Ws;
    const int rowoff = (arr & 1) ? D : 0;
    const int m0 = mt * 64;
    const int tid = threadIdx.x;

    __shared__ float Xs[64][132];       // pad 132: 16B-aligned rows, conflict-light
    __shared__ float Wt[128][64];

    // stage X tile 64x128
    #pragma unroll
    for (int i = 0; i < 8; ++i) {
        int f4 = i * 256 + tid;         // 2048 float4
        int idx = f4 * 4;
        int m = idx >> 7, k = idx & 127;
        float4 v = *(const float4*)&x[(size_t)(m0 + m) * D + k];
        *(float4*)&Xs[m][k] = v;
    }
    // stage W tile 128x64
    #pragma unroll
    for (int i = 0; i < 8; ++i) {
        int f4 = i * 256 + tid;
        int idx = f4 * 4;
        int k = idx >> 6, lc = idx & 63;
        float4 v = *(const float4*)&Wsrc[(size_t)(rowoff + k) * D + c0 + lc];
        *(float4*)&Wt[k][lc] = v;
    }
    __syncthreads();

    const int tr = tid >> 4;   // 0..15  -> rows tr*4..tr*4+3
    const int tc = tid & 15;   // 0..15  -> cols tc*4..tc*4+3

    float acc[4][4] = {};
    for (int k = 0; k < D; k += 4) {
        float4 a[4], w[4];
        #pragma unroll
        for (int im = 0; im < 4; ++im) a[im] = *(const float4*)&Xs[tr * 4 + im][k];
        #pragma unroll
        for (int kk = 0; kk < 4; ++kk) w[kk] = *(const float4*)&Wt[k + kk][tc * 4];
        #pragma unroll
        for (int im = 0; im < 4; ++im) {
            const float* ap = (const float*)&a[im];
            #pragma unroll
            for (int kk = 0; kk < 4; ++kk) {
                const float* wp = (const float*)&w[kk];
                float av = ap[kk];
                acc[im][0] = fmaf(av, wp[0], acc[im][0]);
                acc[im][1] = fmaf(av, wp[1], acc[im][1]);
                acc[im][2] = fmaf(av, wp[2], acc[im][2]);
                acc[im][3] = fmaf(av, wp[3], acc[im][3]);
            }
        }
    }

    // epilogue: centers term + bias, then exp2
    const float sgn   = (arr & 1) ? -1.f : 1.f;   // B side subtracts centers term
    const float scale = (arr < 2) ? -LOG2E : LOG2E; // f-gate: e^{-t}; s-gate: e^{+t}
    float cw0[4], cw1[4], bias[4];
    #pragma unroll
    for (int jn = 0; jn < 4; ++jn) {
        int c = c0 + tc * 4 + jn;
        cw0[jn] = Wsrc[256 * D + c];
        cw1[jn] = Wsrc[257 * D + c];
        bias[jn] = (arr == 0) ? bf[c] : ((arr == 2) ? bs[c] : 0.f);
    }
    float* obase = out + (size_t)arr * NN * D;
    #pragma unroll
    for (int im = 0; im < 4; ++im) {
        int n = m0 + tr * 4 + im;
        float ce0 = centers[2 * n], ce1 = centers[2 * n + 1];
        float4 v;
        float* vp = (float*)&v;
        #pragma unroll
        for (int jn = 0; jn < 4; ++jn) {
            float t = acc[im][jn] + bias[jn] + sgn * fmaf(ce0, cw0[jn], ce1 * cw1[jn]);
            vp[jn] = __builtin_amdgcn_exp2f(scale * t);
        }
        *(float4*)&obase[(size_t)n * D + c0 + tc * 4] = v;
    }
}

// ---------------------------------------------------------------------------
// Kernel 2: edge aggregation within each 64-agent clique.
//   agg[d][c] = sum_{j != d} sigmoid(Af[d]+Bf[j]) * softplus(As[d]+Bs[j])
//             = sum rcp(1 + EAf[d]*EBf[j]) * log2(1 + EAs[d]*EBs[j]) * ln2
// Only 2 transcendentals per element (rcp, log2); exps hoisted to prep.
// Full j-sum then subtract j=d self term (branch-free).
// grid = 128 samples x 4 dst-groups; block 256 = 2 dst-halves x 128 channels.
// Each thread owns 8 (d,c) pairs fully -> no atomics for agg.
// Also emits per-block partial sums (s1,s2 per channel) for batch-norm stats.
// ---------------------------------------------------------------------------
__global__ __launch_bounds__(256) void edge_kernel(
    const float* __restrict__ EAf, const float* __restrict__ EBf,
    const float* __restrict__ EAs, const float* __restrict__ EBs,
    float* __restrict__ agg,        // [NN][D]
    float* __restrict__ partials)   // [512][256]: s1[128], s2[128]
{
    const int s = blockIdx.x >> 2;
    const int g = blockIdx.x & 3;
    const int tid = threadIdx.x;
    const int c  = tid & 127;
    const int dh = tid >> 7;
    const int nbase = s * AGENTS;

    __shared__ float Bfs[AGENTS][D];
    __shared__ float Bss[AGENTS][D];

    #pragma unroll
    for (int i = 0; i < 8; ++i) {
        int f4 = i * 256 + tid;
        int idx = f4 * 4;
        int j = idx >> 7, cc = idx & 127;
        *(float4*)&Bfs[j][cc] = *(const float4*)&EBf[(size_t)(nbase + j) * D + cc];
        *(float4*)&Bss[j][cc] = *(const float4*)&EBs[(size_t)(nbase + j) * D + cc];
    }
    __syncthreads();

    const int d0 = g * 16 + dh * 8;
    float eaf[8], eas[8], acc[8];
    #pragma unroll
    for (int i = 0; i < 8; ++i) {
        int n = nbase + d0 + i;
        eaf[i] = EAf[(size_t)n * D + c];
        eas[i] = EAs[(size_t)n * D + c];
        acc[i] = 0.f;
    }

    for (int j = 0; j < AGENTS; ++j) {
        float ebf = Bfs[j][c];
        float ebs = Bss[j][c];
        #pragma unroll
        for (int i = 0; i < 8; ++i) {
            float sg = __builtin_amdgcn_rcpf(1.f + eaf[i] * ebf);
            float lg = __builtin_amdgcn_logf(1.f + eas[i] * ebs);
            acc[i] += sg * lg;
        }
    }

    // subtract self term, scale by ln2, store agg, accumulate stats
    float s1 = 0.f, s2 = 0.f;
    #pragma unroll
    for (int i = 0; i < 8; ++i) {
        int j = d0 + i;
        float sg = __builtin_amdgcn_rcpf(1.f + eaf[i] * Bfs[j][c]);
        float lg = __builtin_amdgcn_logf(1.f + eas[i] * Bss[j][c]);
        float a = (acc[i] - sg * lg) * LN2;
        agg[(size_t)(nbase + d0 + i) * D + c] = a;
        s1 += a;
        s2 += a * a;
    }

    __syncthreads();               // done reading B tiles; reuse LDS
    if (dh == 1) { Bfs[0][c] = s1; Bss[0][c] = s2; }
    __syncthreads();
    if (dh == 0) {
        s1 += Bfs[0][c];
        s2 += Bss[0][c];
        partials[(size_t)blockIdx.x * 256 + c]       = s1;
        partials[(size_t)blockIdx.x * 256 + 128 + c] = s2;
    }
}

// ---------------------------------------------------------------------------
// Kernel 3: reduce 512 partials -> mu[c], rstd[c].  grid 128 (c), block 256.
// ---------------------------------------------------------------------------
__global__ __launch_bounds__(256) void stats_kernel(
    const float* __restrict__ partials, float* __restrict__ stats)
{
    const int c = blockIdx.x;
    const int t = threadIdx.x;
    float s1 = partials[(size_t)t * 256 + c] + partials[(size_t)(t + 256) * 256 + c];
    float s2 = partials[(size_t)t * 256 + 128 + c] + partials[(size_t)(t + 256) * 256 + 128 + c];
    __shared__ float r1[256], r2[256];
    r1[t] = s1; r2[t] = s2;
    __syncthreads();
    for (int off = 128; off > 0; off >>= 1) {
        if (t < off) { r1[t] += r1[t + off]; r2[t] += r2[t + off]; }
        __syncthreads();
    }
    if (t == 0) {
        float mu = r1[0] * (1.f / NN);
        float var = r2[0] * (1.f / NN) - mu * mu;
        stats[c]     = mu;
        stats[D + c] = rsqrtf(var + EPSF);
    }
}

// ---------------------------------------------------------------------------
// Kernel 4: BN + residual + relu.  out = relu((agg-mu)*rstd*gamma + beta + x)
// grid 1024, block 256, float4 per thread.
// ---------------------------------------------------------------------------
__global__ __launch_bounds__(256) void bn_kernel(
    const float* __restrict__ agg, const float* __restrict__ xin,
    const float* __restrict__ stats,
    const float* __restrict__ gamma, const float* __restrict__ beta,
    float* __restrict__ outp)
{
    const int t = blockIdx.x * 256 + threadIdx.x;
    const int n = t >> 5;
    const int c = (t & 31) * 4;
    float4 a  = *(const float4*)&agg[(size_t)n * D + c];
    float4 xv = *(const float4*)&xin[(size_t)n * D + c];
    float4 mu = *(const float4*)&stats[c];
    float4 rs = *(const float4*)&stats[D + c];
    float4 gm = *(const float4*)&gamma[c];
    float4 bt = *(const float4*)&beta[c];
    float4 o;
    o.x = fmaxf(0.f, fmaf((a.x - mu.x) * rs.x, gm.x, bt.x) + xv.x);
    o.y = fmaxf(0.f, fmaf((a.y - mu.y) * rs.y, gm.y, bt.y) + xv.y);
    o.z = fmaxf(0.f, fmaf((a.z - mu.z) * rs.z, gm.z, bt.z) + xv.z);
    o.w = fmaxf(0.f, fmaf((a.w - mu.w) * rs.w, gm.w, bt.w) + xv.w);
    *(float4*)&outp[(size_t)n * D + c] = o;
}

// ---------------------------------------------------------------------------
extern "C" void kernel_launch(void* const* d_in, const int* in_sizes, int n_in,
                              void* d_out, int out_size, void* d_ws, size_t ws_size,
                              hipStream_t stream) {
    const float* x0      = (const float*)d_in[0];
    const float* centers = (const float*)d_in[1];
    // d_in[2], d_in[3]: edge lists — structure is deterministic, unused.
    const float* Wf[2] = { (const float*)d_in[4],  (const float*)d_in[10] };
    const float* bf[2] = { (const float*)d_in[5],  (const float*)d_in[11] };
    const float* Ws[2] = { (const float*)d_in[6],  (const float*)d_in[12] };
    const float* bs[2] = { (const float*)d_in[7],  (const float*)d_in[13] };
    const float* gm[2] = { (const float*)d_in[8],  (const float*)d_in[14] };
    const float* bt[2] = { (const float*)d_in[9],  (const float*)d_in[15] };

    float* ws       = (float*)d_ws;
    const size_t ND = (size_t)NN * D;     // 1048576
    float* AB       = ws;                 // 4*ND floats
    float* agg      = ws + 4 * ND;
    float* x1       = ws + 5 * ND;
    float* partials = ws + 6 * ND;        // 512*256
    float* stats    = partials + 512 * 256;

    float* outp = (float*)d_out;

    const float* xin = x0;
    for (int l = 0; l < 2; ++l) {
        float* xout = (l == 0) ? x1 : outp;
        prep_kernel<<<dim3(1024), dim3(256), 0, stream>>>(
            xin, centers, Wf[l], bf[l], Ws[l], bs[l], AB);
        edge_kernel<<<dim3(512), dim3(256), 0, stream>>>(
            AB, AB + ND, AB + 2 * ND, AB + 3 * ND, agg, partials);
        stats_kernel<<<dim3(128), dim3(256), 0, stream>>>(partials, stats);
        bn_kernel<<<dim3(1024), dim3(256), 0, stream>>>(
            agg, xin, stats, gm[l], bt[l], xout);
        xin = x1;
    }
}